// Round 1
// baseline (2398.248 us; speedup 1.0000x reference)
//
#include <hip/hip_runtime.h>
#include <stdint.h>

// SEQ=256, B=64, DIM=1024, UNITS=1024, 4U=4096
typedef unsigned short ushort_t;
typedef __attribute__((ext_vector_type(8))) short s16x8;
typedef __attribute__((ext_vector_type(4))) float f32x4;
typedef __attribute__((ext_vector_type(4))) unsigned short u16x4;

#define TO_GLB(p) ((const __attribute__((address_space(1))) void*)(p))
#define TO_LDS(p) ((__attribute__((address_space(3))) void*)(p))

__device__ __forceinline__ ushort_t f2bf(float f) {
  union { float f; uint32_t u; } v; v.f = f;
  uint32_t u = v.u;
  uint32_t r = (u + 0x7FFFu + ((u >> 16) & 1u)) >> 16;
  return (ushort_t)r;
}
__device__ __forceinline__ float bf2f(ushort_t b) {
  union { uint32_t u; float f; } v; v.u = ((uint32_t)b) << 16;
  return v.f;
}
__device__ __forceinline__ float sigm(float x) {
  x = fminf(fmaxf(x, -30.f), 30.f);
  return 1.0f / (1.0f + __expf(-x));
}
__device__ __forceinline__ float tanh_f(float x) {
  x = fminf(fmaxf(x, -15.f), 15.f);
  float t = __expf(2.0f * x);
  return (t - 1.0f) / (t + 1.0f);
}

// ---------------- convert f32 -> bf16, 4 elems/thread ----------------
__global__ void conv_f32_to_bf16(const float* __restrict__ src,
                                 ushort_t* __restrict__ dst, int n4) {
  int i = blockIdx.x * blockDim.x + threadIdx.x;
  if (i < n4) {
    float4 v = ((const float4*)src)[i];
    u16x4 o;
    o[0] = f2bf(v.x); o[1] = f2bf(v.y); o[2] = f2bf(v.z); o[3] = f2bf(v.w);
    *(u16x4*)(dst + 4 * (size_t)i) = o;
  }
}

// ---------------- init h0 (bf16) and c (f32) from hx/cx ----------------
__global__ void init_hc(const float* __restrict__ hx, const float* __restrict__ cx,
                        ushort_t* __restrict__ h0, float* __restrict__ cb, int n) {
  int i = blockIdx.x * blockDim.x + threadIdx.x;
  if (i < n) { h0[i] = f2bf(hx[i]); cb[i] = cx[i]; }
}

// ---------------- x_proj GEMM: C[16384][4096] = A[16384][1024] @ B[4096][1024]^T + bias ----
// m97 structure: 128x128 tile, BK=32, 4 waves (2x2), global_load_lds width 16.
__global__ __launch_bounds__(256) void gemm_xproj(
    const ushort_t* __restrict__ A,   // x bf16 [16384][1024]
    const ushort_t* __restrict__ Bw,  // W_ih bf16 [4096][1024]
    const float* __restrict__ b_ih, const float* __restrict__ b_hh,
    ushort_t* __restrict__ C)         // x_proj bf16 [16384][4096]
{
  __shared__ ushort_t As[128 * 32];
  __shared__ ushort_t Bs[128 * 32];
  const int t = threadIdx.x;
  const int lane = t & 63;
  const int wid = t >> 6;
  const int wr = wid >> 1, wc = wid & 1;
  const size_t tm = (size_t)blockIdx.x * 128;
  const size_t tn = (size_t)blockIdx.y * 128;

  f32x4 acc[4][4];
  const f32x4 zero = {0.f, 0.f, 0.f, 0.f};
#pragma unroll
  for (int m = 0; m < 4; m++)
#pragma unroll
    for (int n = 0; n < 4; n++) acc[m][n] = zero;

  for (int k0 = 0; k0 < 1024; k0 += 32) {
    __syncthreads();
#pragma unroll
    for (int i = 0; i < 2; i++) {
      int row = i * 64 + (t >> 2);
      int kc = (t & 3) * 8;
      const ushort_t* ga = A + (tm + row) * 1024 + k0 + kc;
      __builtin_amdgcn_global_load_lds(TO_GLB(ga),
          TO_LDS((char*)As + (i * 256 + wid * 64) * 16), 16, 0, 0);
      const ushort_t* gb = Bw + (tn + row) * 1024 + k0 + kc;
      __builtin_amdgcn_global_load_lds(TO_GLB(gb),
          TO_LDS((char*)Bs + (i * 256 + wid * 64) * 16), 16, 0, 0);
    }
    __syncthreads();
    s16x8 af[4], bfr[4];
#pragma unroll
    for (int m = 0; m < 4; m++) {
      int r = wr * 64 + m * 16 + (lane & 15);
      af[m] = *(const s16x8*)((const char*)As + r * 64 + (lane >> 4) * 16);
    }
#pragma unroll
    for (int n = 0; n < 4; n++) {
      int r = wc * 64 + n * 16 + (lane & 15);
      bfr[n] = *(const s16x8*)((const char*)Bs + r * 64 + (lane >> 4) * 16);
    }
#pragma unroll
    for (int m = 0; m < 4; m++)
#pragma unroll
      for (int n = 0; n < 4; n++)
        acc[m][n] = __builtin_amdgcn_mfma_f32_16x16x32_bf16(af[m], bfr[n], acc[m][n], 0, 0, 0);
  }

#pragma unroll
  for (int m = 0; m < 4; m++)
#pragma unroll
    for (int n = 0; n < 4; n++)
#pragma unroll
      for (int j = 0; j < 4; j++) {
        size_t row = tm + wr * 64 + m * 16 + ((lane >> 4) << 2) + j;
        int col = (int)tn + wc * 64 + n * 16 + (lane & 15);
        float v = acc[m][n][j] + b_ih[col] + b_hh[col];
        C[row * 4096 + col] = f2bf(v);
      }
}

// ---------------- one LSTM step ----------------
// grid 128 = (64 unit-groups of 16) x (2 batch-halves of 32); 256 threads = 4 waves.
// wave w = gate section w (i,f,g,o). h staged in LDS (XOR-swizzled), W_hh streamed.
__global__ __launch_bounds__(256) void lstm_step(
    const ushort_t* __restrict__ h_prev, ushort_t* __restrict__ h_next,
    float* __restrict__ c_buf,
    const ushort_t* __restrict__ xproj, const float* __restrict__ reset,
    const ushort_t* __restrict__ Whh,
    float* __restrict__ out_h0, float* __restrict__ out_h1, float* __restrict__ out_cs,
    int S)
{
  __shared__ char smem[65536];   // h tile [32][2048B] swizzled; reused for gates f32[4][32][16]
  const int t = threadIdx.x;
  const int lane = t & 63;
  const int sct = t >> 6;            // gate section for this wave
  const int g = blockIdx.x >> 1;
  const int mh = blockIdx.x & 1;
  const int u0 = g * 16;
  const int b0 = mh * 32;

  // phase 1: stage h*mask into LDS (mask is exactly 0/1 -> zero the bits)
  const s16x8 zv = {0, 0, 0, 0, 0, 0, 0, 0};
#pragma unroll
  for (int i = 0; i < 16; i++) {
    int c = i * 256 + t;       // 0..4095
    int r = c >> 7;            // local row 0..31
    int ch = c & 127;          // 16B chunk in row
    int b = b0 + r;
    float m = 1.0f - reset[S * 64 + b];
    s16x8 v = *(const s16x8*)(h_prev + (size_t)b * 1024 + ch * 8);
    if (m == 0.0f) v = zv;
    int off = (r * 2048 + ch * 16) ^ ((r & 7) << 4);
    *(s16x8*)(smem + off) = v;
  }
  __syncthreads();

  // phase 2: K-loop. wave computes [32 batch x 16 units] for its gate section.
  const ushort_t* wbase = Whh + ((size_t)(sct * 1024 + u0 + (lane & 15))) * 1024 + (lane >> 4) * 8;
  const f32x4 zero = {0.f, 0.f, 0.f, 0.f};
  f32x4 acc0 = zero, acc1 = zero;
  s16x8 bpre[4];
#pragma unroll
  for (int i = 0; i < 4; i++) bpre[i] = *(const s16x8*)(wbase + i * 32);
#pragma unroll
  for (int kk = 0; kk < 32; kk++) {
    int ka = kk * 64 + (lane >> 4) * 16;      // byte offset of k-chunk within row
    int r0 = (lane & 15);
    int r1 = 16 + (lane & 15);
    s16x8 a0 = *(const s16x8*)(smem + ((r0 * 2048 + ka) ^ ((r0 & 7) << 4)));
    s16x8 a1 = *(const s16x8*)(smem + ((r1 * 2048 + ka) ^ ((r1 & 7) << 4)));
    s16x8 bc = bpre[kk & 3];
    if (kk + 4 < 32) bpre[kk & 3] = *(const s16x8*)(wbase + (kk + 4) * 32);
    acc0 = __builtin_amdgcn_mfma_f32_16x16x32_bf16(a0, bc, acc0, 0, 0, 0);
    acc1 = __builtin_amdgcn_mfma_f32_16x16x32_bf16(a1, bc, acc1, 0, 0, 0);
  }
  __syncthreads();   // all A-frag reads done before overwriting smem with gates

  // stash gates to LDS: f32 [4][32][16]
  float* gsh = (float*)smem;
#pragma unroll
  for (int j = 0; j < 4; j++) {
    int r0 = (lane >> 4) * 4 + j;
    gsh[(sct * 32 + r0) * 16 + (lane & 15)] = acc0[j];
    gsh[(sct * 32 + 16 + r0) * 16 + (lane & 15)] = acc1[j];
  }
  __syncthreads();

  // phase 3: cell update for 32x16 cells, 2 per thread
#pragma unroll
  for (int ci = 0; ci < 2; ci++) {
    int cell = ci * 256 + t;
    int bl = cell >> 4, c = cell & 15;
    int b = b0 + bl;
    int u = u0 + c;
    size_t xb = ((size_t)S * 64 + b) * 4096 + u;
    float gi = gsh[(0 * 32 + bl) * 16 + c] + bf2f(xproj[xb]);
    float gf = gsh[(1 * 32 + bl) * 16 + c] + bf2f(xproj[xb + 1024]);
    float gg = gsh[(2 * 32 + bl) * 16 + c] + bf2f(xproj[xb + 2048]);
    float go = gsh[(3 * 32 + bl) * 16 + c] + bf2f(xproj[xb + 3072]);
    float m = 1.0f - reset[S * 64 + b];
    float ii = sigm(gi), ff = sigm(gf), G = tanh_f(gg), oo = sigm(go);
    float cp = c_buf[(size_t)b * 1024 + u] * m;
    float cn = ff * cp + ii * G;
    float hn = oo * tanh_f(cn);
    c_buf[(size_t)b * 1024 + u] = cn;
    size_t ob = (size_t)S * 65536 + (size_t)b * 1024 + u;
    out_cs[ob] = cn;
    out_h0[ob] = hn;
    out_h1[ob] = hn;
    h_next[(size_t)b * 1024 + u] = f2bf(hn);
  }
}

extern "C" void kernel_launch(void* const* d_in, const int* in_sizes, int n_in,
                              void* d_out, int out_size, void* d_ws, size_t ws_size,
                              hipStream_t stream) {
  const float* x     = (const float*)d_in[0];
  const float* hx    = (const float*)d_in[1];
  const float* cx    = (const float*)d_in[2];
  const float* reset = (const float*)d_in[3];
  const float* W_ih  = (const float*)d_in[4];
  const float* W_hh  = (const float*)d_in[5];
  const float* b_ih  = (const float*)d_in[6];
  const float* b_hh  = (const float*)d_in[7];
  float* out = (float*)d_out;

  char* ws = (char*)d_ws;
  ushort_t* xbf   = (ushort_t*)(ws);                  // 33,554,432 B
  ushort_t* wihb  = (ushort_t*)(ws + 33554432);       //  8,388,608 B
  ushort_t* whhb  = (ushort_t*)(ws + 41943040);       //  8,388,608 B
  ushort_t* xproj = (ushort_t*)(ws + 50331648);       // 134,217,728 B
  ushort_t* h0    = (ushort_t*)(ws + 184549376);      // 131,072 B
  ushort_t* h1    = (ushort_t*)(ws + 184680448);      // 131,072 B
  float*    cb    = (float*)   (ws + 184811520);      // 262,144 B

  hipLaunchKernelGGL(conv_f32_to_bf16, dim3(16384), dim3(256), 0, stream, x, xbf, 4194304);
  hipLaunchKernelGGL(conv_f32_to_bf16, dim3(4096), dim3(256), 0, stream, W_ih, wihb, 1048576);
  hipLaunchKernelGGL(conv_f32_to_bf16, dim3(4096), dim3(256), 0, stream, W_hh, whhb, 1048576);
  hipLaunchKernelGGL(init_hc, dim3(256), dim3(256), 0, stream, hx, cx, h0, cb, 65536);
  hipLaunchKernelGGL(gemm_xproj, dim3(128, 32), dim3(256), 0, stream, xbf, wihb, b_ih, b_hh, xproj);

  float* oh0 = out;
  float* oh1 = out + 16777216;
  float* ocs = out + 33554432;
  for (int s = 0; s < 256; s++) {
    const ushort_t* hp = (s & 1) ? h1 : h0;
    ushort_t* hn = (s & 1) ? h0 : h1;
    hipLaunchKernelGGL(lstm_step, dim3(128), dim3(256), 0, stream,
                       hp, hn, cb, xproj, reset, whhb, oh0, oh1, ocs, s);
  }
}